// Round 6
// baseline (3596.671 us; speedup 1.0000x reference)
//
#include <hip/hip_runtime.h>

#define T_STEPS 4096
#define BATCH   64
#define INDIM   4
#define H       256
#define OUTD    2
#define NCOL    16
#define CHUNK   16
#define COL_DW  140                   // 128 data + 12 skew (140%32=12 -> 2-way banks, free)
#define SLOT_DW (NCOL*COL_DW)         // 2240 dwords per h slot
#define XCOL_DW 20                    // per-col x: 16 data + 4 pad (20%32 spreads banks)
#define XROW_DW (NCOL*XCOL_DW)        // 320 dwords per staged step
#define XS_DW   (CHUNK*XROW_DW)       // 5120 dwords
#define LDS_DW  (2*SLOT_DW + XS_DW)   // 9600 dw = 38.4 KB

typedef _Float16 h8 __attribute__((ext_vector_type(8)));
typedef float    f4 __attribute__((ext_vector_type(4)));

#define MFMA(A, B, C) __builtin_amdgcn_mfma_f32_16x16x32_f16((A), (B), (C), 0, 0, 0)

__device__ __forceinline__ unsigned pk(float a, float b) {
    return __builtin_bit_cast(unsigned, __builtin_amdgcn_cvt_pkrtz(a, b));
}

__device__ __forceinline__ float fast_tanh(float x) {
    float ax = fabsf(x);
    float e  = __expf(-2.0f * ax);
    float r  = (1.0f - e) * __builtin_amdgcn_rcpf(1.0f + e);
    return copysignf(r, x);
}

// lgkm-only barrier: __syncthreads() emits s_waitcnt vmcnt(0) which would
// drain the head's fire-and-forget global store and the x-chunk prefetch
// every step. Only LDS ordering is needed between steps.
__device__ __forceinline__ void bar_lgkm() {
    asm volatile("s_waitcnt lgkmcnt(0)\n\ts_barrier" ::: "memory");
}

// R5 post-mortem: absmax 0.116 == max|bi+bh| -> the f16 1.0 planted at k=4
// of each xstage column raced with OTHER threads' zero-loop writes (no
// barrier between zero and plant). Plant landing before the zero wiped the
// 1.0 -> bias term dropped for that (s,c). Fix: __syncthreads() between
// zeroing and planting. Pipeline changes from R4 (even/odd MFMA partials,
// head hidden among d-MFMAs, COL_DW=140 bank skew, lgkm-only barrier,
// register x-prefetch) are unchanged and get their first real measurement.
__global__ __attribute__((amdgpu_waves_per_eu(1, 1))) __launch_bounds__(256)
void elman_kernel(const float* __restrict__ input,
                  const float* __restrict__ Wi,
                  const float* __restrict__ bi,
                  const float* __restrict__ Wh,
                  const float* __restrict__ bh,
                  const float* __restrict__ Wf,
                  const float* __restrict__ bf,
                  float* __restrict__ out)
{
    const int t    = threadIdx.x;
    const int w    = t >> 6;          // wave 0..3 -> rows 64w..64w+63
    const int lane = t & 63;
    const int c    = lane & 15;       // batch col within block (MFMA col)
    const int g    = lane >> 4;       // k-group 0..3 (MFMA k-subgroup)
    const int b0   = blockIdx.x * NCOL;

    __shared__ unsigned lds[LDS_DW];
    unsigned* xs = lds + 2 * SLOT_DW;

    // ---- resident A fragments: Wh rows w*64+mt*16+c, k = kt*32+g*8+e ----
    h8 a[4][9];
    #pragma unroll
    for (int mt = 0; mt < 4; ++mt) {
        const int row = w * 64 + mt * 16 + c;
        #pragma unroll
        for (int kt = 0; kt < 8; ++kt) {
            const float* p = Wh + (size_t)row * H + kt * 32 + g * 8;
            float4 x0 = *(const float4*)(p);
            float4 x1 = *(const float4*)(p + 4);
            uint4 u;
            u.x = pk(x0.x, x0.y); u.y = pk(x0.z, x0.w);
            u.z = pk(x1.x, x1.y); u.w = pk(x1.z, x1.w);
            a[mt][kt] = __builtin_bit_cast(h8, u);
        }
        // 9th K-tile: [Wi | bias] against B = [x | 1.0]
        uint4 u = {0u, 0u, 0u, 0u};
        if (g == 0) {
            float4 wi = *(const float4*)(Wi + row * INDIM);
            u.x = pk(wi.x, wi.y);
            u.y = pk(wi.z, wi.w);
            u.z = pk(bi[row] + bh[row], 0.f);
        }
        a[mt][8] = __builtin_bit_cast(h8, u);
    }
    // head A fragments: Wf rows 0..1 in M-rows 0..1, rest zero
    h8 awf[8];
    #pragma unroll
    for (int kt = 0; kt < 8; ++kt) {
        uint4 u = {0u, 0u, 0u, 0u};
        if (c < OUTD) {
            const float* p = Wf + (size_t)c * H + kt * 32 + g * 8;
            float4 x0 = *(const float4*)(p);
            float4 x1 = *(const float4*)(p + 4);
            u.x = pk(x0.x, x0.y); u.y = pk(x0.z, x0.w);
            u.z = pk(x1.x, x1.y); u.w = pk(x1.z, x1.w);
        }
        awf[kt] = __builtin_bit_cast(h8, u);
    }
    const float bf0 = bf[0], bf1 = bf[1];

    // ---- precomputed LDS offsets ----
    const int rdw = c * COL_DW + g * 4;            // B-frag read base (dwords)
    int wb[4];
    #pragma unroll
    for (int m = 0; m < 4; ++m)                    // h write offsets, rows r..r+3
        wb[m] = c * COL_DW + ((2 * w + (m >> 1)) << 4)
              + (((2 * m + (g >> 1)) & 3) << 2) + ((g & 1) << 1);

    // ---- init: zero h slot 0 (= h_{-1}) and xstage ----
    for (int idx = t; idx < SLOT_DW; idx += 256) lds[idx] = 0u;
    for (int idx = t; idx < XS_DW; idx += 256) xs[idx] = 0u;
    __syncthreads();   // R5 bug: plant raced with other threads' zeroes
    {   // plant f16 1.0 at k=4 of every (s, c) x-column (persists: refills
        // only overwrite dwords 0-1)
        const int s = t >> 4, cc = t & 15;
        xs[s * XROW_DW + cc * XCOL_DW + 2] = 0x00003C00u;
    }
    __syncthreads();

    // ---- x prefetch for chunk 0 ----
    const int xsst = t >> 4, xscc = t & 15;        // this thread's staging task
    float4 xp = *(const float4*)(input + ((size_t)xsst * BATCH + b0 + xscc) * INDIM);

    const f4 z4 = {0.f, 0.f, 0.f, 0.f};

    #pragma unroll 2
    for (int i = 0; i < T_STEPS; ++i) {
        if ((i & (CHUNK - 1)) == 0) {
            // write previously-prefetched x for THIS chunk; prefetch next
            unsigned* xd = xs + xsst * XROW_DW + xscc * XCOL_DW;
            xd[0] = pk(xp.x, xp.y);
            xd[1] = pk(xp.z, xp.w);
            __syncthreads();
            const int nc = (i + CHUNK < T_STEPS) ? (i + CHUNK) : i;
            xp = *(const float4*)(input +
                   ((size_t)(nc + xsst) * BATCH + b0 + xscc) * INDIM);
        }

        const unsigned* slotR = lds + (i & 1) * SLOT_DW;
        unsigned*       slotW = lds + ((i & 1) ^ 1) * SLOT_DW;

        // ---- B fragments: h_{i-1} + x-tile ----
        uint4 hv[8];
        #pragma unroll
        for (int kt = 0; kt < 8; ++kt)
            hv[kt] = *(const uint4*)(slotR + rdw + kt * 16);
        uint4 xv = *(const uint4*)(xs + (i & (CHUNK - 1)) * XROW_DW
                                   + c * XCOL_DW + g * 4);
        h8 bb[9];
        #pragma unroll
        for (int kt = 0; kt < 8; ++kt) bb[kt] = __builtin_bit_cast(h8, hv[kt]);
        bb[8] = __builtin_bit_cast(h8, xv);

        // ---- recurrence: 8 independent chains (even/odd kt x 4 M-tiles) ----
        f4 accA[4], accB[4];
        #pragma unroll
        for (int m = 0; m < 4; ++m) accA[m] = MFMA(a[m][0], bb[0], z4);
        #pragma unroll
        for (int m = 0; m < 4; ++m) accB[m] = MFMA(a[m][1], bb[1], z4);
        #pragma unroll
        for (int s = 1; s < 4; ++s) {
            #pragma unroll
            for (int m = 0; m < 4; ++m)
                accA[m] = MFMA(a[m][2 * s], bb[2 * s], accA[m]);
            #pragma unroll
            for (int m = 0; m < 4; ++m)
                accB[m] = MFMA(a[m][2 * s + 1], bb[2 * s + 1], accB[m]);
        }
        #pragma unroll
        for (int m = 0; m < 4; ++m) accA[m] = MFMA(a[m][8], bb[8], accA[m]);

        // ---- rotating head (out[i-1]): 2x4-deep, latency hides in d-section
        if (i && ((i & 3) == w)) {
            f4 hA = MFMA(awf[0], bb[0], z4);
            f4 hB = MFMA(awf[1], bb[1], z4);
            hA = MFMA(awf[2], bb[2], hA);
            hB = MFMA(awf[3], bb[3], hB);
            hA = MFMA(awf[4], bb[4], hA);
            hB = MFMA(awf[5], bb[5], hB);
            hA = MFMA(awf[6], bb[6], hA);
            hB = MFMA(awf[7], bb[7], hB);
            if (g == 0) {
                float2 o2 = { fast_tanh(hA.x + hB.x + bf0),
                              fast_tanh(hA.y + hB.y + bf1) };
                *(float2*)(out + ((size_t)(i - 1) * BATCH + b0 + c) * OUTD) = o2;
            }
        }

        // ---- tanh + pack + store h_i ----
        #pragma unroll
        for (int m = 0; m < 4; ++m) {
            f4 d = accA[m] + accB[m];
            float h0 = fast_tanh(d.x);
            float h1 = fast_tanh(d.y);
            float h2 = fast_tanh(d.z);
            float h3 = fast_tanh(d.w);
            uint2 ph = { pk(h0, h1), pk(h2, h3) };
            *(uint2*)(slotW + wb[m]) = ph;
        }

        bar_lgkm();   // LDS ordering only; global stores/prefetch stay in flight
    }

    // ---- final head: out[4095] from h_4095 (slot T_STEPS&1 = 0) ----
    if (w == 0) {
        const unsigned* hb = lds;
        f4 hA = z4, hB = z4;
        #pragma unroll
        for (int kt = 0; kt < 8; ++kt) {
            uint4 u = *(const uint4*)(hb + rdw + kt * 16);
            h8 bv = __builtin_bit_cast(h8, u);
            if (kt & 1) hB = MFMA(awf[kt], bv, hB);
            else        hA = MFMA(awf[kt], bv, hA);
        }
        if (g == 0) {
            float2 o2 = { fast_tanh(hA.x + hB.x + bf0),
                          fast_tanh(hA.y + hB.y + bf1) };
            *(float2*)(out + ((size_t)(T_STEPS - 1) * BATCH + b0 + c) * OUTD) = o2;
        }
    }
}

extern "C" void kernel_launch(void* const* d_in, const int* in_sizes, int n_in,
                              void* d_out, int out_size, void* d_ws, size_t ws_size,
                              hipStream_t stream) {
    const float* input = (const float*)d_in[0];
    // d_in[1] = target (unused by forward)
    const float* Wi = (const float*)d_in[2];
    const float* bi = (const float*)d_in[3];
    const float* Wh = (const float*)d_in[4];
    const float* bh = (const float*)d_in[5];
    const float* Wf = (const float*)d_in[6];
    const float* bf = (const float*)d_in[7];
    float* out = (float*)d_out;

    elman_kernel<<<dim3(BATCH / NCOL), dim3(256), 0, stream>>>(
        input, Wi, bi, Wh, bh, Wf, bf, out);
}

// Round 7
// 2111.092 us; speedup vs baseline: 1.7037x; 1.7037x over previous
//
#include <hip/hip_runtime.h>

#define T_STEPS 4096
#define BATCH   64
#define INDIM   4
#define H       256
#define OUTD    2
#define CHUNK   32
#define SLOT_DW 36                    // dwords per k-quarter: 32 + 4 skew
#define ENT_DW  (4*SLOT_DW)           // 144 dwords per stored h vector
#define ENT_B   (4*ENT_DW)            // 576 bytes
#define RING_DW (CHUNK*ENT_DW)        // 4608 dwords (18 KB)
#define WF_DW   (OUTD*(H/2))          // 256 dwords packed Wf
#define XS_DW   (CHUNK*INDIM)         // 128 dwords: staged x for the chunk

typedef __fp16 half2v __attribute__((ext_vector_type(2)));

__device__ __forceinline__ float fast_tanh(float x) {
    float ax = fabsf(x);
    float e  = __expf(-2.0f * ax);
    float r  = (1.0f - e) * __builtin_amdgcn_rcpf(1.0f + e);
    return copysignf(r, x);
}

// quad_perm butterfly add: CTRL=0xB1 is lane^1, CTRL=0x4E is lane^2
template<int CTRL>
__device__ __forceinline__ float qadd(float a) {
    int s = __builtin_amdgcn_update_dpp(0, __builtin_bit_cast(int, a),
                                        CTRL, 0xf, 0xf, true);
    return a + __builtin_bit_cast(float, s);
}
#define QX1 0xB1
#define QX2 0x4E

// R6 post-mortem: the MFMA path concentrates 16 tanh/lane/step on 4 CUs
// (~500+cy of quarter-rate transcendentals) — structural floor above R2's
// 1786us. Pivot back to the 64-block fdot2 structure (R2, verified).
// R7's single change: split each row's k-accumulation into even/odd-dword
// chains (8 accumulators instead of 4). In R2 the 4 dwords of each uint4
// fed ONE chain back-to-back (4-instr spacing); if fdot2 is 2cy-issue with
// ~16cy latency, that spacing mimics half-rate. 8 chains space dependent
// updates 8 instrs (~16cy) apart -> issue-bound if (b) holds.
__global__ __attribute__((amdgpu_waves_per_eu(1, 1))) __launch_bounds__(256)
void elman_kernel(const float* __restrict__ input,
                  const float* __restrict__ Wi,
                  const float* __restrict__ bi,
                  const float* __restrict__ Wh,
                  const float* __restrict__ bh,
                  const float* __restrict__ Wf,
                  const float* __restrict__ bf,
                  float* __restrict__ out)
{
    const int b  = blockIdx.x;
    const int t  = threadIdx.x;
    const int q  = t >> 2;        // quad id 0..63 -> rows 4q..4q+3
    const int ko = t & 3;         // k-quarter
    const int k0 = ko * 64;

    __shared__ unsigned int lds[RING_DW + WF_DW + XS_DW];
    unsigned int* ring   = lds;
    unsigned int* wf_pk  = lds + RING_DW;
    float*        xstage = (float*)(lds + RING_DW + WF_DW);

    // --- weights: 4 rows x 64 k packed f16 -> 128 dwords (resident) ---
    half2v w[4][32];
    #pragma unroll
    for (int r = 0; r < 4; ++r) {
        const float* p = Wh + (size_t)(4 * q + r) * H + k0;
        #pragma unroll
        for (int j = 0; j < 16; ++j) {
            float4 a = *(const float4*)(p + 4 * j);
            w[r][2 * j]     = __builtin_amdgcn_cvt_pkrtz(a.x, a.y);
            w[r][2 * j + 1] = __builtin_amdgcn_cvt_pkrtz(a.z, a.w);
        }
    }
    #pragma unroll
    for (int r = 0; r < 4; ++r)
        #pragma unroll
        for (int j = 0; j < 32; ++j) {
            float f = __builtin_bit_cast(float, w[r][j]);
            asm volatile("" : "+v"(f));
            w[r][j] = __builtin_bit_cast(half2v, f);
        }

    // each lane finalizes row t  (row = 4q + ko = t)
    const float4 wim   = *(const float4*)(Wi + t * INDIM);
    const float  biasm = bi[t] + bh[t];
    const float  bf0   = bf[0], bf1 = bf[1];
    const int    boff  = (t >> 6) * (SLOT_DW * 4) + (t & 63) * 2;  // bytes

    {   // pack Wf: all 256 lanes
        const int o = t >> 7, e = t & 127;
        wf_pk[t] = __builtin_bit_cast(unsigned int,
            __builtin_amdgcn_cvt_pkrtz(Wf[o * H + 2 * e], Wf[o * H + 2 * e + 1]));
    }
    if (t < H / 2) ring[(CHUNK - 1) * ENT_DW + (t >> 5) * SLOT_DW + (t & 31)] = 0u;
    __syncthreads();

    const unsigned int rd_off = (unsigned int)(ko * SLOT_DW);

    for (int chunk = 0; chunk < T_STEPS / CHUNK; ++chunk) {
        // ---- stage this chunk's x into LDS (only VMEM reads per chunk) ----
        if (t < CHUNK) {
            const int s = chunk * CHUNK + t;
            ((float4*)xstage)[t] = *(const float4*)(input + ((size_t)s * BATCH + b) * INDIM);
        }
        __syncthreads();   // drains the staging loads ONCE per chunk

        #pragma unroll 1
        for (int i = 0; i < CHUNK; ++i) {
            const unsigned int* hb =
                ring + ((i + CHUNK - 1) & (CHUNK - 1)) * ENT_DW + rd_off;
            uint4 hv[8];
            #pragma unroll
            for (int j = 0; j < 8; ++j) hv[j] = *(const uint4*)(hb + 4 * j);
            const float4 xs = *((const float4*)xstage + i);

            // 8 chains: (row, dword-parity). Dependent reuse of a chain is
            // 8 instructions apart (d0 vs d2) -> ~16cy slack.
            float a0A = 0.f, a0B = 0.f, a1A = 0.f, a1B = 0.f;
            float a2A = 0.f, a2B = 0.f, a3A = 0.f, a3B = 0.f;
            #pragma unroll
            for (int j = 0; j < 8; ++j) {
                half2v h0 = __builtin_bit_cast(half2v, hv[j].x);
                half2v h1 = __builtin_bit_cast(half2v, hv[j].y);
                half2v h2 = __builtin_bit_cast(half2v, hv[j].z);
                half2v h3 = __builtin_bit_cast(half2v, hv[j].w);
                a0A = __builtin_amdgcn_fdot2(w[0][4 * j],     h0, a0A, false);
                a1A = __builtin_amdgcn_fdot2(w[1][4 * j],     h0, a1A, false);
                a2A = __builtin_amdgcn_fdot2(w[2][4 * j],     h0, a2A, false);
                a3A = __builtin_amdgcn_fdot2(w[3][4 * j],     h0, a3A, false);
                a0B = __builtin_amdgcn_fdot2(w[0][4 * j + 1], h1, a0B, false);
                a1B = __builtin_amdgcn_fdot2(w[1][4 * j + 1], h1, a1B, false);
                a2B = __builtin_amdgcn_fdot2(w[2][4 * j + 1], h1, a2B, false);
                a3B = __builtin_amdgcn_fdot2(w[3][4 * j + 1], h1, a3B, false);
                a0A = __builtin_amdgcn_fdot2(w[0][4 * j + 2], h2, a0A, false);
                a1A = __builtin_amdgcn_fdot2(w[1][4 * j + 2], h2, a1A, false);
                a2A = __builtin_amdgcn_fdot2(w[2][4 * j + 2], h2, a2A, false);
                a3A = __builtin_amdgcn_fdot2(w[3][4 * j + 2], h2, a3A, false);
                a0B = __builtin_amdgcn_fdot2(w[0][4 * j + 3], h3, a0B, false);
                a1B = __builtin_amdgcn_fdot2(w[1][4 * j + 3], h3, a1B, false);
                a2B = __builtin_amdgcn_fdot2(w[2][4 * j + 3], h3, a2B, false);
                a3B = __builtin_amdgcn_fdot2(w[3][4 * j + 3], h3, a3B, false);
            }
            float acc0 = a0A + a0B;
            float acc1 = a1A + a1B;
            float acc2 = a2A + a2B;
            float acc3 = a3A + a3B;

            // quad butterfly reduce with early select:
            // stage 1 (lane^1): pair partial sums; pick accs by row parity.
            // stage 2 (lane^2): cross-pair sums; pick by bit1.
            // Result: lane ko holds full sum of row 4q+ko == t.
            acc0 = qadd<QX1>(acc0);
            acc1 = qadd<QX1>(acc1);
            acc2 = qadd<QX1>(acc2);
            acc3 = qadd<QX1>(acc3);
            float A  = (ko & 1) ? acc1 : acc0;
            float Bv = (ko & 1) ? acc3 : acc2;
            A  = qadd<QX2>(A);
            Bv = qadd<QX2>(Bv);
            float accm = (ko & 2) ? Bv : A;

            float pre = accm + biasm +
                xs.x * wim.x + xs.y * wim.y + xs.z * wim.z + xs.w * wim.w;
            __fp16 h16 = (__fp16)fast_tanh(pre);
            *(__fp16*)((char*)ring + i * ENT_B + boff) = h16;

            __syncthreads();   // no VMEM in flight during steps: drain is free
        }

        // --- deferred output head: 64 tasks x 4 lanes ---
        {
            const int task = t >> 2;      // 0..63
            const int s    = task >> 1;   // step in chunk
            const int o    = task & 1;    // output channel
            const int sub  = t & 3;       // k-quarter
            const unsigned int* hp = ring + s * ENT_DW + sub * SLOT_DW;
            const unsigned int* wp = wf_pk + o * (H / 2) + sub * 32;

            float acc = 0.f;
            #pragma unroll
            for (int j = 0; j < 8; ++j) {
                uint4 hq = *(const uint4*)(hp + 4 * j);
                uint4 wq = *(const uint4*)(wp + 4 * j);
                acc = __builtin_amdgcn_fdot2(__builtin_bit_cast(half2v, wq.x),
                                             __builtin_bit_cast(half2v, hq.x), acc, false);
                acc = __builtin_amdgcn_fdot2(__builtin_bit_cast(half2v, wq.y),
                                             __builtin_bit_cast(half2v, hq.y), acc, false);
                acc = __builtin_amdgcn_fdot2(__builtin_bit_cast(half2v, wq.z),
                                             __builtin_bit_cast(half2v, hq.z), acc, false);
                acc = __builtin_amdgcn_fdot2(__builtin_bit_cast(half2v, wq.w),
                                             __builtin_bit_cast(half2v, hq.w), acc, false);
            }
            acc = qadd<QX1>(acc);
            acc = qadd<QX2>(acc);

            if (sub == 0) {
                out[((size_t)(chunk * CHUNK + s) * BATCH + b) * OUTD + o] =
                    fast_tanh(acc + (o ? bf1 : bf0));
            }
            __syncthreads();  // protect ring before next chunk overwrites
        }
    }
}

extern "C" void kernel_launch(void* const* d_in, const int* in_sizes, int n_in,
                              void* d_out, int out_size, void* d_ws, size_t ws_size,
                              hipStream_t stream) {
    const float* input = (const float*)d_in[0];
    // d_in[1] = target (unused by forward)
    const float* Wi = (const float*)d_in[2];
    const float* bi = (const float*)d_in[3];
    const float* Wh = (const float*)d_in[4];
    const float* bh = (const float*)d_in[5];
    const float* Wf = (const float*)d_in[6];
    const float* bf = (const float*)d_in[7];
    float* out = (float*)d_out;

    elman_kernel<<<dim3(BATCH), dim3(256), 0, stream>>>(
        input, Wi, bi, Wh, bh, Wf, bf, out);
}

// Round 10
// 1891.519 us; speedup vs baseline: 1.9015x; 1.1161x over previous
//
#include <hip/hip_runtime.h>

#define T_STEPS 4096
#define BATCH   64
#define INDIM   4
#define H       256
#define OUTD    2
#define CHUNK   32
#define SLICE_DW 20                   // per-oct k-slice: 16 data + 4 pad dwords
#define ENT_DW   168                  // 8 slices * 20 + 8 tail pad
#define RING_DW (CHUNK*ENT_DW)        // 5376 dwords (21.5 KB)
#define WF_DW   (OUTD*(H/2))          // 256 dwords packed Wf
#define XS_DW   (CHUNK*INDIM)         // 128 dwords staged x

typedef _Float16 half2v __attribute__((ext_vector_type(2)));

__device__ __forceinline__ float fast_tanh(float x) {
    float ax = fabsf(x);
    float e  = __expf(-2.0f * ax);
    float r  = (1.0f - e) * __builtin_amdgcn_rcpf(1.0f + e);
    return copysignf(r, x);
}

template<int CTRL>
__device__ __forceinline__ float qadd(float a) {
    int s = __builtin_amdgcn_update_dpp(0, __builtin_bit_cast(int, a),
                                        CTRL, 0xf, 0xf, true);
    return a + __builtin_bit_cast(float, s);
}
template<int CTRL>
__device__ __forceinline__ float dppmov(float a) {
    int s = __builtin_amdgcn_update_dpp(0, __builtin_bit_cast(int, a),
                                        CTRL, 0xf, 0xf, true);
    return __builtin_bit_cast(float, s);
}
#define QX1  0xB1   // quad_perm lane^1
#define QX2  0x4E   // quad_perm lane^2
// R9 BUG + FIX: DPP row-shift direction. Verified via R0's working
// dpp_radd<SHL2>,<SHL1> -> "sum into lane 0", which is only consistent with
//   row_shl:N  (0x100+N):  D[i] = S[i+N]   (data moves to LOWER lanes)
//   row_shr:N  (0x110+N):  D[i] = S[i-N]   (data moves to HIGHER lanes)
// R8/R9 had these swapped in the ^4 stage -> rows 4..7 of each oct got
// bound-ctrl zeros or cross-oct garbage -> deterministic absmax 0.246
// identical across accumulation formats (tanh-saturated). One-line fix.
#define RSHL4 0x104 // row_shl:4  D[i]=S[i+4]
#define RSHR4 0x114 // row_shr:4  D[i]=S[i-4]

__device__ __forceinline__ half2v pkh(float a, float b) {
    return __builtin_bit_cast(half2v, __builtin_amdgcn_cvt_pkrtz(a, b));
}

// Oct layout (8 rows x 32 k per lane) with fdot2 f32 accumulation —
// R2's proven numerics, same 128-fdot2 issue floor, but the DS convoy
// shrinks 36 -> 20 b128 reads/CU (432 -> 240 cy) and the slice stride of
// 20 dw puts the 8 oct addresses on 8 disjoint 4-bank spans: conflict-free.
__global__ __attribute__((amdgpu_waves_per_eu(1, 1))) __launch_bounds__(256)
void elman_kernel(const float* __restrict__ input,
                  const float* __restrict__ Wi,
                  const float* __restrict__ bi,
                  const float* __restrict__ Wh,
                  const float* __restrict__ bh,
                  const float* __restrict__ Wf,
                  const float* __restrict__ bf,
                  float* __restrict__ out)
{
    const int b  = blockIdx.x;
    const int t  = threadIdx.x;
    const int Q  = t >> 3;        // oct id 0..31 -> rows 8Q..8Q+7
    const int o  = t & 7;         // k-eighth AND final row-within-oct
    const int k0 = o * 32;

    __shared__ unsigned int lds[RING_DW + WF_DW + XS_DW];
    unsigned int* ring   = lds;
    unsigned int* wf_pk  = lds + RING_DW;
    float*        xstage = (float*)(lds + RING_DW + WF_DW);

    // --- weights: 8 rows x 32 k packed f16 -> 128 dwords (resident) ---
    half2v w[8][16];
    #pragma unroll
    for (int r = 0; r < 8; ++r) {
        const float* p = Wh + (size_t)(8 * Q + r) * H + k0;
        #pragma unroll
        for (int m = 0; m < 8; ++m) {
            float4 a = *(const float4*)(p + 4 * m);
            w[r][2 * m]     = pkh(a.x, a.y);
            w[r][2 * m + 1] = pkh(a.z, a.w);
        }
    }
    #pragma unroll
    for (int r = 0; r < 8; ++r)
        #pragma unroll
        for (int j = 0; j < 16; ++j) {
            int f = __builtin_bit_cast(int, w[r][j]);
            asm volatile("" : "+v"(f));
            w[r][j] = __builtin_bit_cast(half2v, f);
        }

    // each lane finalizes row t (row = 8Q + o = t)
    const float4 wim   = *(const float4*)(Wi + t * INDIM);
    const float  biasm = bi[t] + bh[t];
    const float  bf0   = bf[0], bf1 = bf[1];
    // h_i write: byte offset within entry = slice(row>>5)*80 + (row&31)*2
    const int    boff  = (t >> 5) * (SLICE_DW * 4) + (t & 31) * 2;

    {   // pack Wf: all 256 lanes
        const int oc = t >> 7, e = t & 127;
        wf_pk[t] = __builtin_bit_cast(unsigned int,
            __builtin_amdgcn_cvt_pkrtz(Wf[oc * H + 2 * e], Wf[oc * H + 2 * e + 1]));
    }
    if (t < ENT_DW) ring[(CHUNK - 1) * ENT_DW + t] = 0u;   // h_{-1} = 0
    __syncthreads();

    const unsigned int rd_off = (unsigned int)(o * SLICE_DW);

    for (int chunk = 0; chunk < T_STEPS / CHUNK; ++chunk) {
        // ---- stage this chunk's x into LDS (only VMEM reads per chunk) ----
        if (t < CHUNK) {
            const int s = chunk * CHUNK + t;
            ((float4*)xstage)[t] = *(const float4*)(input + ((size_t)s * BATCH + b) * INDIM);
        }
        __syncthreads();

        #pragma unroll 1
        for (int i = 0; i < CHUNK; ++i) {
            const unsigned int* hb =
                ring + ((i + CHUNK - 1) & (CHUNK - 1)) * ENT_DW + rd_off;
            uint4 hv[4];
            #pragma unroll
            for (int j = 0; j < 4; ++j) hv[j] = *(const uint4*)(hb + 4 * j);
            const float4 xs = *((const float4*)xstage + i);

            // 8 rows x 16 fdot2 (f32 accumulate): 8 independent chains
            float accf[8];
            #pragma unroll
            for (int r = 0; r < 8; ++r) accf[r] = 0.f;
            #pragma unroll
            for (int j = 0; j < 4; ++j) {
                half2v h0 = __builtin_bit_cast(half2v, hv[j].x);
                half2v h1 = __builtin_bit_cast(half2v, hv[j].y);
                half2v h2 = __builtin_bit_cast(half2v, hv[j].z);
                half2v h3 = __builtin_bit_cast(half2v, hv[j].w);
                #pragma unroll
                for (int r = 0; r < 8; ++r)
                    accf[r] = __builtin_amdgcn_fdot2(w[r][4 * j],     h0, accf[r], false);
                #pragma unroll
                for (int r = 0; r < 8; ++r)
                    accf[r] = __builtin_amdgcn_fdot2(w[r][4 * j + 1], h1, accf[r], false);
                #pragma unroll
                for (int r = 0; r < 8; ++r)
                    accf[r] = __builtin_amdgcn_fdot2(w[r][4 * j + 2], h2, accf[r], false);
                #pragma unroll
                for (int r = 0; r < 8; ++r)
                    accf[r] = __builtin_amdgcn_fdot2(w[r][4 * j + 3], h3, accf[r], false);
            }

            // ---- oct butterfly reduce with early select ----
            // stage ^1: pairs complete over 64k; keep rows with bit0 == o&1
            #pragma unroll
            for (int r = 0; r < 8; ++r) accf[r] = qadd<QX1>(accf[r]);
            float s4_0 = (o & 1) ? accf[1] : accf[0];   // row 0+b0
            float s4_1 = (o & 1) ? accf[3] : accf[2];   // row 2+b0
            float s4_2 = (o & 1) ? accf[5] : accf[4];   // row 4+b0
            float s4_3 = (o & 1) ? accf[7] : accf[6];   // row 6+b0
            // stage ^2: complete over 128k; keep rows with bit1 == (o>>1)&1
            s4_0 = qadd<QX2>(s4_0);
            s4_1 = qadd<QX2>(s4_1);
            s4_2 = qadd<QX2>(s4_2);
            s4_3 = qadd<QX2>(s4_3);
            float s0 = (o & 2) ? s4_1 : s4_0;           // row 2b1+b0
            float s1 = (o & 2) ? s4_3 : s4_2;           // row 4+2b1+b0
            // stage ^4: cross-quad (other 128k). partner = lane o^4.
            // o&4==0 lanes need S[i+4] -> row_shl:4 ; o&4 lanes S[i-4] -> row_shr:4
            {
                float u0 = dppmov<RSHL4>(s0), v0 = dppmov<RSHR4>(s0);
                float u1 = dppmov<RSHL4>(s1), v1 = dppmov<RSHR4>(s1);
                s0 += (o & 4) ? v0 : u0;
                s1 += (o & 4) ? v1 : u1;
            }
            float accm = (o & 4) ? s1 : s0;             // row o (full 256k)

            float pre = accm + biasm +
                xs.x * wim.x + xs.y * wim.y + xs.z * wim.z + xs.w * wim.w;
            __fp16 h16 = (__fp16)fast_tanh(pre);
            *(__fp16*)((char*)ring + i * (ENT_DW * 4) + boff) = h16;

            __syncthreads();
        }

        // --- deferred output head: 64 tasks x 4 lanes ---
        {
            const int task = t >> 2;      // 0..63
            const int s    = task >> 1;   // step in chunk
            const int oc   = task & 1;    // output channel
            const int sub  = t & 3;       // k-quarter (= slices 2sub, 2sub+1)
            const unsigned int* hp = ring + s * ENT_DW + sub * 2 * SLICE_DW;
            const unsigned int* wp = wf_pk + oc * (H / 2) + sub * 32;

            float acc = 0.f;
            #pragma unroll
            for (int j = 0; j < 8; ++j) {
                const unsigned int* hj = (j < 4) ? (hp + 4 * j)
                                                 : (hp + SLICE_DW + 4 * (j - 4));
                uint4 hq = *(const uint4*)(hj);
                uint4 wq = *(const uint4*)(wp + 4 * j);
                acc = __builtin_amdgcn_fdot2(__builtin_bit_cast(half2v, wq.x),
                                             __builtin_bit_cast(half2v, hq.x), acc, false);
                acc = __builtin_amdgcn_fdot2(__builtin_bit_cast(half2v, wq.y),
                                             __builtin_bit_cast(half2v, hq.y), acc, false);
                acc = __builtin_amdgcn_fdot2(__builtin_bit_cast(half2v, wq.z),
                                             __builtin_bit_cast(half2v, hq.z), acc, false);
                acc = __builtin_amdgcn_fdot2(__builtin_bit_cast(half2v, wq.w),
                                             __builtin_bit_cast(half2v, hq.w), acc, false);
            }
            acc = qadd<QX1>(acc);
            acc = qadd<QX2>(acc);

            if (sub == 0) {
                out[((size_t)(chunk * CHUNK + s) * BATCH + b) * OUTD + oc] =
                    fast_tanh(acc + (oc ? bf1 : bf0));
            }
            __syncthreads();  // protect ring before next chunk overwrites
        }
    }
}

extern "C" void kernel_launch(void* const* d_in, const int* in_sizes, int n_in,
                              void* d_out, int out_size, void* d_ws, size_t ws_size,
                              hipStream_t stream) {
    const float* input = (const float*)d_in[0];
    // d_in[1] = target (unused by forward)
    const float* Wi = (const float*)d_in[2];
    const float* bi = (const float*)d_in[3];
    const float* Wh = (const float*)d_in[4];
    const float* bh = (const float*)d_in[5];
    const float* Wf = (const float*)d_in[6];
    const float* bf = (const float*)d_in[7];
    float* out = (float*)d_out;

    elman_kernel<<<dim3(BATCH), dim3(256), 0, stream>>>(
        input, Wi, bi, Wh, bh, Wf, bf, out);
}